// Round 3
// baseline (1259.940 us; speedup 1.0000x reference)
//
#include <hip/hip_runtime.h>

#define HH 383
#define WW 383
#define CINC 64
#define COUTC 128
#define HO 191
#define WO 191
#define MIDN (4L * HO * WO * COUTC)   // 18,690,048 floats

// conv1 tiling
#define NI 8
#define NJ 16
#define ROW_STRIDE 536
#define W_STRIDE 17

// ---------------- zero d_out ----------------
__global__ void zero_f4(float4* __restrict__ p, long n4) {
    long i = blockIdx.x * (long)blockDim.x + threadIdx.x;
    long stride = (long)gridDim.x * blockDim.x;
    float4 z = make_float4(0.f, 0.f, 0.f, 0.f);
    for (; i < n4; i += stride) p[i] = z;
}

// ---------------- scatter features -> dense NHWC (in d_out) ----------------
__global__ void scatter_feats(const float4* __restrict__ feats,
                              const int* __restrict__ coors,
                              float4* __restrict__ dense, int npts) {
    int t = blockIdx.x * blockDim.x + threadIdx.x;
    int total = npts * 16;
    if (t >= total) return;
    int p = t >> 4, q = t & 15;
    int b = coors[3 * p], y = coors[3 * p + 1], x = coors[3 * p + 2];
    dense[(((long)b * HH + y) * WW + x) * 16 + q] = feats[t];
}

// ---------------- misc init: zero row for conv2 + group counters ----------------
__global__ void init_misc(float* __restrict__ zrow, int* __restrict__ cnt) {
    int t = threadIdx.x;
    if (t < 128) zrow[t] = 0.f;
    if (t < 4) cnt[t] = 0;
}

// ---------------- classify points into 4 parity groups ----------------
__global__ void classify(const int* __restrict__ coors, int npts,
                         int* __restrict__ grp, int* __restrict__ cnt) {
    int t = blockIdx.x * blockDim.x + threadIdx.x;
    if (t >= npts) return;
    int y = coors[3 * t + 1], x = coors[3 * t + 2];
    int g = (y & 1) * 2 + (x & 1);
    int k = atomicAdd(&cnt[g], 1);
    grp[g * npts + k] = t;
}

// ---------------- conv1: 3x3 stride-2 VALID, register-tiled implicit GEMM ----------------
__global__ __launch_bounds__(256, 3) void conv1_kern(const float4* __restrict__ dense4,
                                                     const float* __restrict__ W1,
                                                     float* __restrict__ mid) {
    __shared__ float ds[17 * ROW_STRIDE];
    __shared__ float wsm[COUTC * W_STRIDE];

    const int j0 = blockIdx.x * NJ;
    const int i0 = blockIdx.y * NI;
    const int b  = blockIdx.z;
    const int tid = threadIdx.x;
    const int tx = tid & 15;
    const int ty = tid >> 4;
    const int il = ty & 7;
    const int jh = ty >> 3;

    float acc[8][8];
    #pragma unroll
    for (int u = 0; u < 8; ++u)
        #pragma unroll
        for (int r = 0; r < 8; ++r) acc[u][r] = 0.f;

    for (int cc = 0; cc < 4; ++cc) {
        __syncthreads();
        for (int t = tid; t < 17 * 33 * 4; t += 256) {
            int rr  = t / 132;
            int rem = t - rr * 132;
            int xx  = rem >> 2;
            int c4  = rem & 3;
            int gr = 2 * i0 + rr;
            int gx = 2 * j0 + xx;
            float4 v = make_float4(0.f, 0.f, 0.f, 0.f);
            if (gr < HH && gx < WW)
                v = dense4[(((long)b * HH + gr) * WW + gx) * 16 + cc * 4 + c4];
            *(float4*)&ds[rr * ROW_STRIDE + xx * 16 + c4 * 4] = v;
        }

        for (int tap = 0; tap < 9; ++tap) {
            __syncthreads();
            for (int t = tid; t < 2048; t += 256) {
                int ci_l = t >> 7;
                int co   = t & 127;
                wsm[co * W_STRIDE + ci_l] = W1[(tap * 64 + cc * 16 + ci_l) * 128 + co];
            }
            __syncthreads();

            const int ky = tap / 3, kx = tap - ky * 3;
            const int drow  = (2 * il + ky) * ROW_STRIDE;
            const int dcol0 = (jh * 16 + kx) * 16;
            const int wbase = tx * W_STRIDE;

            #pragma unroll 1
            for (int c4 = 0; c4 < 4; ++c4) {
                float4 wv[8], dv[8];
                #pragma unroll
                for (int u = 0; u < 8; ++u)
                    wv[u] = *(const float4*)&wsm[wbase + u * (16 * W_STRIDE) + c4 * 4];
                #pragma unroll
                for (int r = 0; r < 8; ++r)
                    dv[r] = *(const float4*)&ds[drow + dcol0 + r * 32 + c4 * 4];
                #pragma unroll
                for (int u = 0; u < 8; ++u)
                    #pragma unroll
                    for (int r = 0; r < 8; ++r) {
                        acc[u][r] = fmaf(dv[r].x, wv[u].x, acc[u][r]);
                        acc[u][r] = fmaf(dv[r].y, wv[u].y, acc[u][r]);
                        acc[u][r] = fmaf(dv[r].z, wv[u].z, acc[u][r]);
                        acc[u][r] = fmaf(dv[r].w, wv[u].w, acc[u][r]);
                    }
            }
        }
    }

    const int i = i0 + il;
    if (i < HO) {
        #pragma unroll
        for (int r = 0; r < 8; ++r) {
            int j = j0 + jh * 8 + r;
            if (j < WO) {
                long base = (((long)b * HO + i) * WO + j) * COUTC;
                #pragma unroll
                for (int u = 0; u < 8; ++u) mid[base + tx + 16 * u] = acc[u][r];
            }
        }
    }
}

// ---------------- conv2: parity-grouped, weight-stationary masked deconv ----------------
// block = 64 points x 64 channels (4 waves x 16 points). Per tap-slot:
// weights (128m x 64c) staged transposed in LDS; inner loop: 1 LDS b128 (reused
// over 16 points) + 16 wave-uniform mid b128 + 64 FMA.
__global__ __launch_bounds__(256, 4) void conv2_gemm(const float* __restrict__ mid,
                                                     const float* __restrict__ W2,
                                                     const int* __restrict__ coors,
                                                     const int* __restrict__ grp,
                                                     const int* __restrict__ cnt,
                                                     float* __restrict__ out, int npts) {
    __shared__ float wlds[64 * 129];
    __shared__ int meta[64 * 3];

    const int g  = blockIdx.y;
    const int n  = cnt[g];
    const int p0 = blockIdx.x * 64;
    if (p0 >= n) return;
    const int gy = g >> 1, gx = g & 1;
    const int tid = threadIdx.x, c = tid & 63, wid = tid >> 6;

    if (tid < 64) {
        int pp = p0 + tid;
        if (pp < n) {
            int t = grp[g * npts + pp];
            meta[tid * 3 + 0] = coors[3 * t + 0];
            meta[tid * 3 + 1] = coors[3 * t + 1];
            meta[tid * 3 + 2] = coors[3 * t + 2];
        } else {
            meta[tid * 3 + 1] = -1;
        }
    }
    __syncthreads();

    float acc[16];
    #pragma unroll
    for (int q = 0; q < 16; ++q) acc[q] = 0.f;

    const int nsy = gy ? 1 : 2, nsx = gx ? 1 : 2;
    for (int sy = 0; sy < nsy; ++sy) {
        const int ky = gy ? 1 : sy * 2;
        for (int sx = 0; sx < nsx; ++sx) {
            const int kx = gx ? 1 : sx * 2;
            const int tap = ky * 3 + kx;

            __syncthreads();  // previous slot's wlds readers done
            for (int t2 = tid; t2 < 64 * 128; t2 += 256) {
                int cc = t2 & 63, m = t2 >> 6;
                wlds[cc * 129 + m] = W2[(tap * COUTC + m) * CINC + cc];
            }
            __syncthreads();

            int off[16];
            #pragma unroll
            for (int pi = 0; pi < 16; ++pi) {
                int pl = wid * 16 + pi;
                int b = meta[pl * 3 + 0];
                int y = meta[pl * 3 + 1];
                int x = meta[pl * 3 + 2];
                int i = gy ? (y >> 1) : ((y >> 1) - 1 + sy);
                int j = gx ? (x >> 1) : ((x >> 1) - 1 + sx);
                bool ok = (y >= 0) && (unsigned)i < (unsigned)HO && (unsigned)j < (unsigned)WO;
                off[pi] = ok ? ((b * HO + i) * WO + j) * COUTC : (int)MIDN;
            }

            for (int m4 = 0; m4 < 32; ++m4) {
                const float4 wv = *(const float4*)&wlds[c * 129 + m4 * 4];
                #pragma unroll
                for (int pi = 0; pi < 16; ++pi) {
                    const float4 mv = *(const float4*)&mid[off[pi] + m4 * 4];
                    acc[pi] = fmaf(mv.x, wv.x, acc[pi]);
                    acc[pi] = fmaf(mv.y, wv.y, acc[pi]);
                    acc[pi] = fmaf(mv.z, wv.z, acc[pi]);
                    acc[pi] = fmaf(mv.w, wv.w, acc[pi]);
                }
            }
        }
    }

    #pragma unroll
    for (int pi = 0; pi < 16; ++pi) {
        int pl = wid * 16 + pi;
        int b = meta[pl * 3 + 0];
        int y = meta[pl * 3 + 1];
        int x = meta[pl * 3 + 2];
        if (y >= 0)
            out[(((long)b * CINC + c) * HH + y) * WW + x] = acc[pi];
    }
}

extern "C" void kernel_launch(void* const* d_in, const int* in_sizes, int n_in,
                              void* d_out, int out_size, void* d_ws, size_t ws_size,
                              hipStream_t stream) {
    const float* feats = (const float*)d_in[0];
    const int* coors = (const int*)d_in[1];
    const float* W1 = (const float*)d_in[3];
    const float* W2 = (const float*)d_in[4];
    float* out = (float*)d_out;
    int npts = in_sizes[1] / 3;

    // ws layout: mid [0, MIDN) floats | zero row [MIDN, MIDN+128) floats |
    //            grp[4*npts] ints | cnt[4] ints
    float* mid  = (float*)d_ws;
    float* zrow = mid + MIDN;
    int*   grp  = (int*)(zrow + 128);
    int*   cnt  = grp + 4 * npts;

    long n4 = (long)out_size / 4;

    // 1) zero d_out, scatter features into it as dense NHWC
    zero_f4<<<2048, 256, 0, stream>>>((float4*)d_out, n4);
    int sthreads = npts * 16;
    scatter_feats<<<(sthreads + 255) / 256, 256, 0, stream>>>(
        (const float4*)feats, coors, (float4*)d_out, npts);

    // 2) parity classification prepass (independent of conv1)
    init_misc<<<1, 256, 0, stream>>>(zrow, cnt);
    classify<<<(npts + 255) / 256, 256, 0, stream>>>(coors, npts, grp, cnt);

    // 3) conv1: dense (in d_out) -> mid (in d_ws)
    conv1_kern<<<dim3(12, 24, 4), 256, 0, stream>>>((const float4*)d_out, W1, mid);

    // 4) re-zero d_out, then parity-grouped masked deconv into NCHW output
    zero_f4<<<2048, 256, 0, stream>>>((float4*)d_out, n4);
    int pblocks = (npts + 63) / 64;
    conv2_gemm<<<dim3(pblocks, 4), 256, 0, stream>>>(mid, W2, coors, grp, cnt, out, npts);
}

// Round 4
// 785.317 us; speedup vs baseline: 1.6044x; 1.6044x over previous
//
#include <hip/hip_runtime.h>

#define HH 383
#define WW 383
#define CINC 64
#define COUTC 128
#define HO 191
#define WO 191
#define MIDN (4L * HO * WO * COUTC)   // 18,690,048 floats

// conv1 tiling
#define NI 8
#define NJ 16
#define ROW_STRIDE 536
#define W_STRIDE 17

// ---------------- zero d_out ----------------
__global__ void zero_f4(float4* __restrict__ p, long n4) {
    long i = blockIdx.x * (long)blockDim.x + threadIdx.x;
    long stride = (long)gridDim.x * blockDim.x;
    float4 z = make_float4(0.f, 0.f, 0.f, 0.f);
    for (; i < n4; i += stride) p[i] = z;
}

// ---------------- scatter features -> dense NHWC (in d_out) ----------------
__global__ void scatter_feats(const float4* __restrict__ feats,
                              const int* __restrict__ coors,
                              float4* __restrict__ dense, int npts) {
    int t = blockIdx.x * blockDim.x + threadIdx.x;
    int total = npts * 16;
    if (t >= total) return;
    int p = t >> 4, q = t & 15;
    int b = coors[3 * p], y = coors[3 * p + 1], x = coors[3 * p + 2];
    dense[(((long)b * HH + y) * WW + x) * 16 + q] = feats[t];
}

// ---------------- misc init: zero row for conv2 + group counters ----------------
__global__ void init_misc(float* __restrict__ zrow, int* __restrict__ cnt) {
    int t = threadIdx.x;
    if (t < 128) zrow[t] = 0.f;
    if (t < 4) cnt[t] = 0;
}

// ---------------- classify points into 4 parity groups (wave-aggregated atomics) ----------------
__global__ void classify(const int* __restrict__ coors, int npts,
                         int* __restrict__ grp, int* __restrict__ cnt) {
    int t = blockIdx.x * blockDim.x + threadIdx.x;
    int lane = threadIdx.x & 63;
    int g = -1;
    if (t < npts) {
        int y = coors[3 * t + 1], x = coors[3 * t + 2];
        g = (y & 1) * 2 + (x & 1);
    }
    #pragma unroll
    for (int gg = 0; gg < 4; ++gg) {
        unsigned long long mask = __ballot(g == gg);
        if (!mask) continue;
        int leader = __ffsll((long long)mask) - 1;
        int base = 0;
        if (lane == leader) base = atomicAdd(&cnt[gg], __popcll(mask));
        base = __shfl(base, leader);
        if (g == gg) {
            int rank = __popcll(mask & ((1ULL << lane) - 1ULL));
            grp[gg * npts + base + rank] = t;
        }
    }
}

// ---------------- conv1: 3x3 stride-2 VALID, register-tiled implicit GEMM ----------------
__global__ __launch_bounds__(256, 3) void conv1_kern(const float4* __restrict__ dense4,
                                                     const float* __restrict__ W1,
                                                     float* __restrict__ mid) {
    __shared__ float ds[17 * ROW_STRIDE];
    __shared__ float wsm[COUTC * W_STRIDE];

    const int j0 = blockIdx.x * NJ;
    const int i0 = blockIdx.y * NI;
    const int b  = blockIdx.z;
    const int tid = threadIdx.x;
    const int tx = tid & 15;
    const int ty = tid >> 4;
    const int il = ty & 7;
    const int jh = ty >> 3;

    float acc[8][8];
    #pragma unroll
    for (int u = 0; u < 8; ++u)
        #pragma unroll
        for (int r = 0; r < 8; ++r) acc[u][r] = 0.f;

    for (int cc = 0; cc < 4; ++cc) {
        __syncthreads();
        for (int t = tid; t < 17 * 33 * 4; t += 256) {
            int rr  = t / 132;
            int rem = t - rr * 132;
            int xx  = rem >> 2;
            int c4  = rem & 3;
            int gr = 2 * i0 + rr;
            int gx = 2 * j0 + xx;
            float4 v = make_float4(0.f, 0.f, 0.f, 0.f);
            if (gr < HH && gx < WW)
                v = dense4[(((long)b * HH + gr) * WW + gx) * 16 + cc * 4 + c4];
            *(float4*)&ds[rr * ROW_STRIDE + xx * 16 + c4 * 4] = v;
        }

        for (int tap = 0; tap < 9; ++tap) {
            __syncthreads();
            for (int t = tid; t < 2048; t += 256) {
                int ci_l = t >> 7;
                int co   = t & 127;
                wsm[co * W_STRIDE + ci_l] = W1[(tap * 64 + cc * 16 + ci_l) * 128 + co];
            }
            __syncthreads();

            const int ky = tap / 3, kx = tap - ky * 3;
            const int drow  = (2 * il + ky) * ROW_STRIDE;
            const int dcol0 = (jh * 16 + kx) * 16;
            const int wbase = tx * W_STRIDE;

            #pragma unroll 1
            for (int c4 = 0; c4 < 4; ++c4) {
                float4 wv[8], dv[8];
                #pragma unroll
                for (int u = 0; u < 8; ++u)
                    wv[u] = *(const float4*)&wsm[wbase + u * (16 * W_STRIDE) + c4 * 4];
                #pragma unroll
                for (int r = 0; r < 8; ++r)
                    dv[r] = *(const float4*)&ds[drow + dcol0 + r * 32 + c4 * 4];
                #pragma unroll
                for (int u = 0; u < 8; ++u)
                    #pragma unroll
                    for (int r = 0; r < 8; ++r) {
                        acc[u][r] = fmaf(dv[r].x, wv[u].x, acc[u][r]);
                        acc[u][r] = fmaf(dv[r].y, wv[u].y, acc[u][r]);
                        acc[u][r] = fmaf(dv[r].z, wv[u].z, acc[u][r]);
                        acc[u][r] = fmaf(dv[r].w, wv[u].w, acc[u][r]);
                    }
            }
        }
    }

    const int i = i0 + il;
    if (i < HO) {
        #pragma unroll
        for (int r = 0; r < 8; ++r) {
            int j = j0 + jh * 8 + r;
            if (j < WO) {
                long base = (((long)b * HO + i) * WO + j) * COUTC;
                #pragma unroll
                for (int u = 0; u < 8; ++u) mid[base + tx + 16 * u] = acc[u][r];
            }
        }
    }
}

// ---------------- conv2: parity-grouped, weight-stationary masked deconv ----------------
__global__ __launch_bounds__(256, 4) void conv2_gemm(const float* __restrict__ mid,
                                                     const float* __restrict__ W2,
                                                     const int* __restrict__ coors,
                                                     const int* __restrict__ grp,
                                                     const int* __restrict__ cnt,
                                                     float* __restrict__ out, int npts) {
    __shared__ float wlds[64 * 129];
    __shared__ int meta[64 * 3];

    const int g  = blockIdx.y;
    const int n  = cnt[g];
    const int p0 = blockIdx.x * 64;
    if (p0 >= n) return;
    const int gy = g >> 1, gx = g & 1;
    const int tid = threadIdx.x, c = tid & 63, wid = tid >> 6;

    if (tid < 64) {
        int pp = p0 + tid;
        if (pp < n) {
            int t = grp[g * npts + pp];
            meta[tid * 3 + 0] = coors[3 * t + 0];
            meta[tid * 3 + 1] = coors[3 * t + 1];
            meta[tid * 3 + 2] = coors[3 * t + 2];
        } else {
            meta[tid * 3 + 1] = -1;
        }
    }
    __syncthreads();

    float acc[16];
    #pragma unroll
    for (int q = 0; q < 16; ++q) acc[q] = 0.f;

    const int nsy = gy ? 1 : 2, nsx = gx ? 1 : 2;
    for (int sy = 0; sy < nsy; ++sy) {
        const int ky = gy ? 1 : sy * 2;
        for (int sx = 0; sx < nsx; ++sx) {
            const int kx = gx ? 1 : sx * 2;
            const int tap = ky * 3 + kx;

            __syncthreads();
            for (int t2 = tid; t2 < 64 * 128; t2 += 256) {
                int cc = t2 & 63, m = t2 >> 6;
                wlds[cc * 129 + m] = W2[(tap * COUTC + m) * CINC + cc];
            }
            __syncthreads();

            int off[16];
            #pragma unroll
            for (int pi = 0; pi < 16; ++pi) {
                int pl = wid * 16 + pi;
                int b = meta[pl * 3 + 0];
                int y = meta[pl * 3 + 1];
                int x = meta[pl * 3 + 2];
                int i = gy ? (y >> 1) : ((y >> 1) - 1 + sy);
                int j = gx ? (x >> 1) : ((x >> 1) - 1 + sx);
                bool ok = (y >= 0) && (unsigned)i < (unsigned)HO && (unsigned)j < (unsigned)WO;
                off[pi] = ok ? ((b * HO + i) * WO + j) * COUTC : (int)MIDN;
            }

            for (int m4 = 0; m4 < 32; ++m4) {
                const float4 wv = *(const float4*)&wlds[c * 129 + m4 * 4];
                #pragma unroll
                for (int pi = 0; pi < 16; ++pi) {
                    const float4 mv = *(const float4*)&mid[off[pi] + m4 * 4];
                    acc[pi] = fmaf(mv.x, wv.x, acc[pi]);
                    acc[pi] = fmaf(mv.y, wv.y, acc[pi]);
                    acc[pi] = fmaf(mv.z, wv.z, acc[pi]);
                    acc[pi] = fmaf(mv.w, wv.w, acc[pi]);
                }
            }
        }
    }

    #pragma unroll
    for (int pi = 0; pi < 16; ++pi) {
        int pl = wid * 16 + pi;
        int b = meta[pl * 3 + 0];
        int y = meta[pl * 3 + 1];
        int x = meta[pl * 3 + 2];
        if (y >= 0)
            out[(((long)b * CINC + c) * HH + y) * WW + x] = acc[pi];
    }
}

extern "C" void kernel_launch(void* const* d_in, const int* in_sizes, int n_in,
                              void* d_out, int out_size, void* d_ws, size_t ws_size,
                              hipStream_t stream) {
    const float* feats = (const float*)d_in[0];
    const int* coors = (const int*)d_in[1];
    const float* W1 = (const float*)d_in[3];
    const float* W2 = (const float*)d_in[4];
    float* out = (float*)d_out;
    int npts = in_sizes[1] / 3;

    float* mid  = (float*)d_ws;
    float* zrow = mid + MIDN;
    int*   grp  = (int*)(zrow + 128);
    int*   cnt  = grp + 4 * npts;

    long n4 = (long)out_size / 4;

    // 1) zero d_out, scatter features into it as dense NHWC
    zero_f4<<<2048, 256, 0, stream>>>((float4*)d_out, n4);
    int sthreads = npts * 16;
    scatter_feats<<<(sthreads + 255) / 256, 256, 0, stream>>>(
        (const float4*)feats, coors, (float4*)d_out, npts);

    // 2) parity classification prepass
    init_misc<<<1, 256, 0, stream>>>(zrow, cnt);
    classify<<<(npts + 255) / 256, 256, 0, stream>>>(coors, npts, grp, cnt);

    // 3) conv1: dense (in d_out) -> mid (in d_ws)
    conv1_kern<<<dim3(12, 24, 4), 256, 0, stream>>>((const float4*)d_out, W1, mid);

    // 4) re-zero d_out, then parity-grouped masked deconv into NCHW output
    zero_f4<<<2048, 256, 0, stream>>>((float4*)d_out, n4);
    int pblocks = (npts + 63) / 64;
    conv2_gemm<<<dim3(pblocks, 4), 256, 0, stream>>>(mid, W2, coors, grp, cnt, out, npts);
}

// Round 5
// 485.449 us; speedup vs baseline: 2.5954x; 1.6177x over previous
//
#include <hip/hip_runtime.h>

#define HH 383
#define WW 383
#define CINC 64
#define COUTC 128
#define HO 191
#define WO 191
#define MIDN (4L * HO * WO * COUTC)   // 18,690,048 floats

typedef __attribute__((ext_vector_type(8))) short short8;
typedef __attribute__((ext_vector_type(8))) unsigned short ushort8;
typedef __attribute__((ext_vector_type(4))) float f32x4;

static __device__ inline unsigned short f2bf(float f) {
    unsigned u = __float_as_uint(f);
    unsigned r = (u + 0x7FFFu + ((u >> 16) & 1u)) >> 16;
    return (unsigned short)r;
}

// ---------------- zero d_out ----------------
__global__ void zero_f4(float4* __restrict__ p, long n4) {
    long i = blockIdx.x * (long)blockDim.x + threadIdx.x;
    long stride = (long)gridDim.x * blockDim.x;
    float4 z = make_float4(0.f, 0.f, 0.f, 0.f);
    for (; i < n4; i += stride) p[i] = z;
}

// ---------------- scatter features -> dense NHWC bf16 (in d_out) ----------------
__global__ void scatter_feats_bf16(const float* __restrict__ feats,
                                   const int* __restrict__ coors,
                                   unsigned short* __restrict__ dense, int npts) {
    int t = blockIdx.x * blockDim.x + threadIdx.x;
    if (t >= npts * 8) return;
    int p = t >> 3, q = t & 7;
    int b = coors[3 * p], y = coors[3 * p + 1], x = coors[3 * p + 2];
    const float* f = feats + (long)p * 64 + q * 8;
    ushort8 v;
    #pragma unroll
    for (int k = 0; k < 8; ++k) v[k] = f2bf(f[k]);
    *(ushort8*)&dense[(((long)b * HH + y) * WW + x) * 64 + q * 8] = v;
}

// ---------------- pack W1 (f32 HWIO) into bf16 MFMA-B fragment layout ----------------
// W1p[((tap*2+kc)*8+ng)*512 + l*8 + j] = bf16( W1[(tap*64 + kc*32 + (l>>4)*8 + j)*128 + ng*16 + (l&15)] )
__global__ void w1_prep(const float* __restrict__ W1, unsigned short* __restrict__ W1p) {
    int t = blockIdx.x * blockDim.x + threadIdx.x;
    if (t >= 73728) return;
    int j  = t & 7;
    int l  = (t >> 3) & 63;
    int ng = (t >> 9) & 7;
    int tk = t >> 12;           // tap*2 + kc, 0..17
    int tap = tk >> 1, kc = tk & 1;
    int ci = kc * 32 + (l >> 4) * 8 + j;
    int co = ng * 16 + (l & 15);
    W1p[t] = f2bf(W1[(tap * 64 + ci) * 128 + co]);
}

// ---------------- misc init: zero row for conv2 + group counters ----------------
__global__ void init_misc(float* __restrict__ zrow, int* __restrict__ cnt) {
    int t = threadIdx.x;
    if (t < 128) zrow[t] = 0.f;
    if (t < 4) cnt[t] = 0;
}

// ---------------- classify points into 4 parity groups (wave-aggregated atomics) ----------------
__global__ void classify(const int* __restrict__ coors, int npts,
                         int* __restrict__ grp, int* __restrict__ cnt) {
    int t = blockIdx.x * blockDim.x + threadIdx.x;
    int lane = threadIdx.x & 63;
    int g = -1;
    if (t < npts) {
        int y = coors[3 * t + 1], x = coors[3 * t + 2];
        g = (y & 1) * 2 + (x & 1);
    }
    #pragma unroll
    for (int gg = 0; gg < 4; ++gg) {
        unsigned long long mask = __ballot(g == gg);
        if (!mask) continue;
        int leader = __ffsll((long long)mask) - 1;
        int base = 0;
        if (lane == leader) base = atomicAdd(&cnt[gg], __popcll(mask));
        base = __shfl(base, leader);
        if (g == gg) {
            int rank = __popcll(mask & ((1ULL << lane) - 1ULL));
            grp[gg * npts + base + rank] = t;
        }
    }
}

// ---------------- conv1: 3x3 stride-2 VALID via bf16 MFMA implicit GEMM ----------------
// block: 256 thr = 4 waves. tile: 32 positions (row i, j=j0..j0+31) x 128 cout.
// wave w: all 32 pos, couts [32w, 32w+32). K = 9 taps x 64 ci = 18 chunks of 32.
// A from LDS-staged dense tile (XOR-swizzled, bits 3-5), B from packed global W1p.
__global__ __launch_bounds__(256, 4) void conv1_mfma(const unsigned short* __restrict__ dense,
                                                     const unsigned short* __restrict__ W1p,
                                                     float* __restrict__ mid) {
    __shared__ unsigned short lds[3 * 66 * 64];  // 25,344 B
    const int j0 = blockIdx.x * 32;
    const int i  = blockIdx.y;
    const int b  = blockIdx.z;
    const int tid = threadIdx.x;
    const int w = tid >> 6, l = tid & 63;

    // stage rows 2i..2i+2, x = 2*j0 .. 2*j0+65, all 64 ci (bf16)
    for (int t = tid; t < 3 * 66 * 8; t += 256) {
        int r = t / 528;
        int rem = t - r * 528;
        int xx = rem >> 3, c8 = rem & 7;
        int gx = 2 * j0 + xx;
        uint4 v = make_uint4(0u, 0u, 0u, 0u);
        if (gx < WW)
            v = *(const uint4*)&dense[(((long)b * HH + (2 * i + r)) * WW + gx) * 64 + c8 * 8];
        int sidx = (r * 66 + xx) * 64 + ((c8 ^ ((xx >> 1) & 7)) << 3);
        *(uint4*)&lds[sidx] = v;
    }
    __syncthreads();

    const int pj0 = l & 15;
    const int hi8 = (l >> 4) * 8;
    f32x4 zf = {0.f, 0.f, 0.f, 0.f};
    f32x4 acc[2][2] = {{zf, zf}, {zf, zf}};

    for (int ky = 0; ky < 3; ++ky) {
        for (int kx = 0; kx < 3; ++kx) {
            const int tap = ky * 3 + kx;
            #pragma unroll
            for (int kc = 0; kc < 2; ++kc) {
                int fo = (((tap * 2 + kc) * 8 + 2 * w) << 9) + l * 8;
                short8 b0 = *(const short8*)&W1p[fo];
                short8 b1 = *(const short8*)&W1p[fo + 512];
                #pragma unroll
                for (int mt = 0; mt < 2; ++mt) {
                    int pj = pj0 + mt * 16;
                    int xx = 2 * pj + kx;
                    int idx = ((ky * 66 + xx) * 64 + kc * 32 + hi8) ^ (((xx >> 1) & 7) << 3);
                    short8 a = *(const short8*)&lds[idx];
                    acc[mt][0] = __builtin_amdgcn_mfma_f32_16x16x32_bf16(a, b0, acc[mt][0], 0, 0, 0);
                    acc[mt][1] = __builtin_amdgcn_mfma_f32_16x16x32_bf16(a, b1, acc[mt][1], 0, 0, 0);
                }
            }
        }
    }

    // epilogue: C/D layout col = l&15, row = (l>>4)*4 + reg (m89-verified)
    const int n0 = 32 * w + (l & 15);
    const int rowbase = (l >> 4) * 4;
    #pragma unroll
    for (int mt = 0; mt < 2; ++mt) {
        #pragma unroll
        for (int reg = 0; reg < 4; ++reg) {
            int j = j0 + mt * 16 + rowbase + reg;
            if (j < WO) {
                long base = (((long)b * HO + i) * WO + j) * COUTC;
                mid[base + n0]      = acc[mt][0][reg];
                mid[base + n0 + 16] = acc[mt][1][reg];
            }
        }
    }
}

// ---------------- conv2: parity-grouped, weight-stationary masked deconv (fp32, unchanged) ----------------
__global__ __launch_bounds__(256, 4) void conv2_gemm(const float* __restrict__ mid,
                                                     const float* __restrict__ W2,
                                                     const int* __restrict__ coors,
                                                     const int* __restrict__ grp,
                                                     const int* __restrict__ cnt,
                                                     float* __restrict__ out, int npts) {
    __shared__ float wlds[64 * 129];
    __shared__ int meta[64 * 3];

    const int g  = blockIdx.y;
    const int n  = cnt[g];
    const int p0 = blockIdx.x * 64;
    if (p0 >= n) return;
    const int gy = g >> 1, gx = g & 1;
    const int tid = threadIdx.x, c = tid & 63, wid = tid >> 6;

    if (tid < 64) {
        int pp = p0 + tid;
        if (pp < n) {
            int t = grp[g * npts + pp];
            meta[tid * 3 + 0] = coors[3 * t + 0];
            meta[tid * 3 + 1] = coors[3 * t + 1];
            meta[tid * 3 + 2] = coors[3 * t + 2];
        } else {
            meta[tid * 3 + 1] = -1;
        }
    }
    __syncthreads();

    float acc[16];
    #pragma unroll
    for (int q = 0; q < 16; ++q) acc[q] = 0.f;

    const int nsy = gy ? 1 : 2, nsx = gx ? 1 : 2;
    for (int sy = 0; sy < nsy; ++sy) {
        const int ky = gy ? 1 : sy * 2;
        for (int sx = 0; sx < nsx; ++sx) {
            const int kx = gx ? 1 : sx * 2;
            const int tap = ky * 3 + kx;

            __syncthreads();
            for (int t2 = tid; t2 < 64 * 128; t2 += 256) {
                int cc = t2 & 63, m = t2 >> 6;
                wlds[cc * 129 + m] = W2[(tap * COUTC + m) * CINC + cc];
            }
            __syncthreads();

            int off[16];
            #pragma unroll
            for (int pi = 0; pi < 16; ++pi) {
                int pl = wid * 16 + pi;
                int b = meta[pl * 3 + 0];
                int y = meta[pl * 3 + 1];
                int x = meta[pl * 3 + 2];
                int i = gy ? (y >> 1) : ((y >> 1) - 1 + sy);
                int j = gx ? (x >> 1) : ((x >> 1) - 1 + sx);
                bool ok = (y >= 0) && (unsigned)i < (unsigned)HO && (unsigned)j < (unsigned)WO;
                off[pi] = ok ? ((b * HO + i) * WO + j) * COUTC : (int)MIDN;
            }

            for (int m4 = 0; m4 < 32; ++m4) {
                const float4 wv = *(const float4*)&wlds[c * 129 + m4 * 4];
                #pragma unroll
                for (int pi = 0; pi < 16; ++pi) {
                    const float4 mv = *(const float4*)&mid[off[pi] + m4 * 4];
                    acc[pi] = fmaf(mv.x, wv.x, acc[pi]);
                    acc[pi] = fmaf(mv.y, wv.y, acc[pi]);
                    acc[pi] = fmaf(mv.z, wv.z, acc[pi]);
                    acc[pi] = fmaf(mv.w, wv.w, acc[pi]);
                }
            }
        }
    }

    #pragma unroll
    for (int pi = 0; pi < 16; ++pi) {
        int pl = wid * 16 + pi;
        int b = meta[pl * 3 + 0];
        int y = meta[pl * 3 + 1];
        int x = meta[pl * 3 + 2];
        if (y >= 0)
            out[(((long)b * CINC + c) * HH + y) * WW + x] = acc[pi];
    }
}

extern "C" void kernel_launch(void* const* d_in, const int* in_sizes, int n_in,
                              void* d_out, int out_size, void* d_ws, size_t ws_size,
                              hipStream_t stream) {
    const float* feats = (const float*)d_in[0];
    const int* coors = (const int*)d_in[1];
    const float* W1 = (const float*)d_in[3];
    const float* W2 = (const float*)d_in[4];
    float* out = (float*)d_out;
    int npts = in_sizes[1] / 3;

    // d_ws layout: mid [MIDN floats] | zrow[128] | grp[4*npts] | cnt[4]
    float* mid  = (float*)d_ws;
    float* zrow = mid + MIDN;
    int*   grp  = (int*)(zrow + 128);
    int*   cnt  = grp + 4 * npts;

    // d_out doubles as scratch before the final output:
    //   [0, 75.1MB): dense bf16   [120MB, 120.15MB): packed W1 bf16 fragments
    unsigned short* denseB = (unsigned short*)d_out;
    unsigned short* W1p = (unsigned short*)((float*)d_out + 30000000L);

    long n4 = (long)out_size / 4;

    // 1) pack W1; zero dense region; scatter features as bf16 dense NHWC
    w1_prep<<<288, 256, 0, stream>>>(W1, W1p);
    zero_f4<<<2048, 256, 0, stream>>>((float4*)d_out, n4 / 2);
    scatter_feats_bf16<<<(npts * 8 + 255) / 256, 256, 0, stream>>>(feats, coors, denseB, npts);

    // 2) parity classification prepass
    init_misc<<<1, 256, 0, stream>>>(zrow, cnt);
    classify<<<(npts + 255) / 256, 256, 0, stream>>>(coors, npts, grp, cnt);

    // 3) conv1 via MFMA: dense bf16 (in d_out) -> mid fp32 (in d_ws)
    conv1_mfma<<<dim3(6, HO, 4), 256, 0, stream>>>(denseB, W1p, mid);

    // 4) re-zero all of d_out (wipes dense + W1p), then masked deconv -> NCHW out
    zero_f4<<<2048, 256, 0, stream>>>((float4*)d_out, n4);
    int pblocks = (npts + 63) / 64;
    conv2_gemm<<<dim3(pblocks, 4), 256, 0, stream>>>(mid, W2, coors, grp, cnt, out, npts);
}

// Round 6
// 266.288 us; speedup vs baseline: 4.7315x; 1.8230x over previous
//
#include <hip/hip_runtime.h>

#define HH 383
#define WW 383
#define CINC 64
#define COUTC 128
#define HO 191
#define WO 191
#define MIDN (4L * HO * WO * COUTC)   // 18,690,048 elements

typedef __attribute__((ext_vector_type(8))) short short8;
typedef __attribute__((ext_vector_type(8))) unsigned short ushort8;
typedef __attribute__((ext_vector_type(4))) float f32x4;

static __device__ inline unsigned short f2bf(float f) {
    unsigned u = __float_as_uint(f);
    unsigned r = (u + 0x7FFFu + ((u >> 16) & 1u)) >> 16;
    return (unsigned short)r;
}

// ---------------- zero d_out ----------------
__global__ void zero_f4(float4* __restrict__ p, long n4) {
    long i = blockIdx.x * (long)blockDim.x + threadIdx.x;
    long stride = (long)gridDim.x * blockDim.x;
    float4 z = make_float4(0.f, 0.f, 0.f, 0.f);
    for (; i < n4; i += stride) p[i] = z;
}

// ---------------- scatter features -> dense NHWC bf16 (in d_out) ----------------
__global__ void scatter_feats_bf16(const float* __restrict__ feats,
                                   const int* __restrict__ coors,
                                   unsigned short* __restrict__ dense, int npts) {
    int t = blockIdx.x * blockDim.x + threadIdx.x;
    if (t >= npts * 8) return;
    int p = t >> 3, q = t & 7;
    int b = coors[3 * p], y = coors[3 * p + 1], x = coors[3 * p + 2];
    const float* f = feats + (long)p * 64 + q * 8;
    ushort8 v;
    #pragma unroll
    for (int k = 0; k < 8; ++k) v[k] = f2bf(f[k]);
    *(ushort8*)&dense[(((long)b * HH + y) * WW + x) * 64 + q * 8] = v;
}

// ---------------- pack W1 (f32 HWIO) into bf16 MFMA-B fragment layout ----------------
__global__ void w1_prep(const float* __restrict__ W1, unsigned short* __restrict__ W1p) {
    int t = blockIdx.x * blockDim.x + threadIdx.x;
    if (t >= 73728) return;
    int j  = t & 7;
    int l  = (t >> 3) & 63;
    int ng = (t >> 9) & 7;
    int tk = t >> 12;           // tap*2 + kc
    int tap = tk >> 1, kc = tk & 1;
    int ci = kc * 32 + (l >> 4) * 8 + j;
    int co = ng * 16 + (l & 15);
    W1p[t] = f2bf(W1[(tap * 64 + ci) * 128 + co]);
}

// ---------------- pack W2 (f32 HWIO, [tap][m][c]) into bf16 MFMA-B fragments ----------------
// W2p[((tap*4+kc)*4+ng)*512 + l*8 + j] = bf16( W2[(tap*128 + kc*32+(l>>4)*8+j)*64 + ng*16+(l&15)] )
__global__ void w2_prep(const float* __restrict__ W2, unsigned short* __restrict__ W2p) {
    int t = blockIdx.x * blockDim.x + threadIdx.x;
    if (t >= 73728) return;
    int j   = t & 7;
    int l   = (t >> 3) & 63;
    int ng  = (t >> 9) & 3;
    int kc  = (t >> 11) & 3;
    int tap = t >> 13;          // 0..8
    int m = kc * 32 + (l >> 4) * 8 + j;
    int c = ng * 16 + (l & 15);
    W2p[t] = f2bf(W2[(tap * 128 + m) * 64 + c]);
}

// ---------------- misc init: bf16 zero row + group counters ----------------
__global__ void init_misc(unsigned short* __restrict__ zrow, int* __restrict__ cnt) {
    int t = threadIdx.x;
    if (t < 128) zrow[t] = 0;
    if (t < 4) cnt[t] = 0;
}

// ---------------- classify points into 4 parity groups (wave-aggregated atomics) ----------------
__global__ void classify(const int* __restrict__ coors, int npts,
                         int* __restrict__ grp, int* __restrict__ cnt) {
    int t = blockIdx.x * blockDim.x + threadIdx.x;
    int lane = threadIdx.x & 63;
    int g = -1;
    if (t < npts) {
        int y = coors[3 * t + 1], x = coors[3 * t + 2];
        g = (y & 1) * 2 + (x & 1);
    }
    #pragma unroll
    for (int gg = 0; gg < 4; ++gg) {
        unsigned long long mask = __ballot(g == gg);
        if (!mask) continue;
        int leader = __ffsll((long long)mask) - 1;
        int base = 0;
        if (lane == leader) base = atomicAdd(&cnt[gg], __popcll(mask));
        base = __shfl(base, leader);
        if (g == gg) {
            int rank = __popcll(mask & ((1ULL << lane) - 1ULL));
            grp[gg * npts + base + rank] = t;
        }
    }
}

// ---------------- conv1: 3x3 stride-2 VALID via bf16 MFMA implicit GEMM ----------------
__global__ __launch_bounds__(256, 4) void conv1_mfma(const unsigned short* __restrict__ dense,
                                                     const unsigned short* __restrict__ W1p,
                                                     unsigned short* __restrict__ mid) {
    __shared__ unsigned short lds[3 * 66 * 64];
    const int j0 = blockIdx.x * 32;
    const int i  = blockIdx.y;
    const int b  = blockIdx.z;
    const int tid = threadIdx.x;
    const int w = tid >> 6, l = tid & 63;

    for (int t = tid; t < 3 * 66 * 8; t += 256) {
        int r = t / 528;
        int rem = t - r * 528;
        int xx = rem >> 3, c8 = rem & 7;
        int gx = 2 * j0 + xx;
        uint4 v = make_uint4(0u, 0u, 0u, 0u);
        if (gx < WW)
            v = *(const uint4*)&dense[(((long)b * HH + (2 * i + r)) * WW + gx) * 64 + c8 * 8];
        int sidx = (r * 66 + xx) * 64 + ((c8 ^ ((xx >> 1) & 7)) << 3);
        *(uint4*)&lds[sidx] = v;
    }
    __syncthreads();

    const int pj0 = l & 15;
    const int hi8 = (l >> 4) * 8;
    f32x4 zf = {0.f, 0.f, 0.f, 0.f};
    f32x4 acc[2][2] = {{zf, zf}, {zf, zf}};

    for (int ky = 0; ky < 3; ++ky) {
        for (int kx = 0; kx < 3; ++kx) {
            const int tap = ky * 3 + kx;
            #pragma unroll
            for (int kc = 0; kc < 2; ++kc) {
                int fo = (((tap * 2 + kc) * 8 + 2 * w) << 9) + l * 8;
                short8 b0 = *(const short8*)&W1p[fo];
                short8 b1 = *(const short8*)&W1p[fo + 512];
                #pragma unroll
                for (int mt = 0; mt < 2; ++mt) {
                    int pj = pj0 + mt * 16;
                    int xx = 2 * pj + kx;
                    int idx = ((ky * 66 + xx) * 64 + kc * 32 + hi8) ^ (((xx >> 1) & 7) << 3);
                    short8 a = *(const short8*)&lds[idx];
                    acc[mt][0] = __builtin_amdgcn_mfma_f32_16x16x32_bf16(a, b0, acc[mt][0], 0, 0, 0);
                    acc[mt][1] = __builtin_amdgcn_mfma_f32_16x16x32_bf16(a, b1, acc[mt][1], 0, 0, 0);
                }
            }
        }
    }

    const int n0 = 32 * w + (l & 15);
    const int rowbase = (l >> 4) * 4;
    #pragma unroll
    for (int mt = 0; mt < 2; ++mt) {
        #pragma unroll
        for (int reg = 0; reg < 4; ++reg) {
            int j = j0 + mt * 16 + rowbase + reg;
            if (j < WO) {
                long base = (((long)b * HO + i) * WO + j) * COUTC;
                mid[base + n0]      = f2bf(acc[mt][0][reg]);
                mid[base + n0 + 16] = f2bf(acc[mt][1][reg]);
            }
        }
    }
}

// ---------------- conv2: parity-grouped masked deconv via bf16 MFMA gather-GEMM ----------------
// block = 64 points x 64 couts, 4 waves; wave w: points [16w,16w+16) x all 64 couts.
// Per (tap,kc): A = per-lane 16B gather from mid rows; B = coalesced packed W2p frags.
__global__ __launch_bounds__(256, 4) void conv2_mfma(const unsigned short* __restrict__ mid,
                                                     const unsigned short* __restrict__ W2p,
                                                     const int* __restrict__ coors,
                                                     const int* __restrict__ grp,
                                                     const int* __restrict__ cnt,
                                                     float* __restrict__ out, int npts) {
    __shared__ int meta[64 * 3];

    const int g  = blockIdx.y;
    const int n  = cnt[g];
    const int p0 = blockIdx.x * 64;
    if (p0 >= n) return;
    const int gy = g >> 1, gx = g & 1;
    const int tid = threadIdx.x, l = tid & 63, w = tid >> 6;

    if (tid < 64) {
        int pp = p0 + tid;
        if (pp < n) {
            int t = grp[g * npts + pp];
            meta[tid * 3 + 0] = coors[3 * t + 0];
            meta[tid * 3 + 1] = coors[3 * t + 1];
            meta[tid * 3 + 2] = coors[3 * t + 2];
        } else {
            meta[tid * 3 + 1] = -1;
        }
    }
    __syncthreads();

    // A-gather identity for this lane: point = 16w + (l&15), k-slice = (l>>4)*8
    const int pA = w * 16 + (l & 15);
    const int bA = meta[pA * 3 + 0];
    const int yA = meta[pA * 3 + 1];
    const int xA = meta[pA * 3 + 2];
    const int hi8 = (l >> 4) * 8;

    f32x4 zf = {0.f, 0.f, 0.f, 0.f};
    f32x4 acc[4] = {zf, zf, zf, zf};

    const int nsy = gy ? 1 : 2, nsx = gx ? 1 : 2;
    for (int sy = 0; sy < nsy; ++sy) {
        const int ky = gy ? 1 : sy * 2;
        const int i  = gy ? (yA >> 1) : ((yA >> 1) - 1 + sy);
        for (int sx = 0; sx < nsx; ++sx) {
            const int kx = gx ? 1 : sx * 2;
            const int j  = gx ? (xA >> 1) : ((xA >> 1) - 1 + sx);
            const int tap = ky * 3 + kx;
            bool ok = (yA >= 0) && (unsigned)i < (unsigned)HO && (unsigned)j < (unsigned)WO;
            int offA = ok ? ((bA * HO + i) * WO + j) * COUTC : (int)MIDN;

            #pragma unroll
            for (int kc = 0; kc < 4; ++kc) {
                short8 a = *(const short8*)&mid[offA + kc * 32 + hi8];
                const unsigned short* wp = &W2p[((tap * 4 + kc) * 4) * 512 + l * 8];
                short8 b0 = *(const short8*)&wp[0];
                short8 b1 = *(const short8*)&wp[512];
                short8 b2 = *(const short8*)&wp[1024];
                short8 b3 = *(const short8*)&wp[1536];
                acc[0] = __builtin_amdgcn_mfma_f32_16x16x32_bf16(a, b0, acc[0], 0, 0, 0);
                acc[1] = __builtin_amdgcn_mfma_f32_16x16x32_bf16(a, b1, acc[1], 0, 0, 0);
                acc[2] = __builtin_amdgcn_mfma_f32_16x16x32_bf16(a, b2, acc[2], 0, 0, 0);
                acc[3] = __builtin_amdgcn_mfma_f32_16x16x32_bf16(a, b3, acc[3], 0, 0, 0);
            }
        }
    }

    // epilogue: D col = l&15 (cout within group), row = (l>>4)*4+reg (point within m-tile)
    #pragma unroll
    for (int reg = 0; reg < 4; ++reg) {
        int pl = w * 16 + (l >> 4) * 4 + reg;
        int b = meta[pl * 3 + 0];
        int y = meta[pl * 3 + 1];
        int x = meta[pl * 3 + 2];
        if (y >= 0) {
            int base = ((b * CINC) * HH + y) * WW + x;
            #pragma unroll
            for (int ng = 0; ng < 4; ++ng) {
                int c = ng * 16 + (l & 15);
                out[base + c * (HH * WW)] = acc[ng][reg];
            }
        }
    }
}

extern "C" void kernel_launch(void* const* d_in, const int* in_sizes, int n_in,
                              void* d_out, int out_size, void* d_ws, size_t ws_size,
                              hipStream_t stream) {
    const float* feats = (const float*)d_in[0];
    const int* coors = (const int*)d_in[1];
    const float* W1 = (const float*)d_in[3];
    const float* W2 = (const float*)d_in[4];
    float* out = (float*)d_out;
    int npts = in_sizes[1] / 3;

    // d_ws layout: mid bf16 [MIDN ushorts] | zrow bf16[128] | grp[4*npts] ints | cnt[4] | W2p[73728] ushorts
    unsigned short* midB  = (unsigned short*)d_ws;
    unsigned short* zrowB = midB + MIDN;
    int*   grp = (int*)(zrowB + 128);
    int*   cnt = grp + 4 * npts;
    unsigned short* W2p = (unsigned short*)(cnt + 4);

    // d_out scratch: [0, 75.1MB) dense bf16; [120MB, +147KB) packed W1
    unsigned short* denseB = (unsigned short*)d_out;
    unsigned short* W1p = (unsigned short*)((float*)d_out + 30000000L);

    long n4 = (long)out_size / 4;

    // 1) pack weights; zero dense region; scatter features as bf16 dense NHWC
    w1_prep<<<288, 256, 0, stream>>>(W1, W1p);
    w2_prep<<<288, 256, 0, stream>>>(W2, W2p);
    zero_f4<<<2048, 256, 0, stream>>>((float4*)d_out, n4 / 2);
    scatter_feats_bf16<<<(npts * 8 + 255) / 256, 256, 0, stream>>>(feats, coors, denseB, npts);

    // 2) parity classification prepass
    init_misc<<<1, 256, 0, stream>>>(zrowB, cnt);
    classify<<<(npts + 255) / 256, 256, 0, stream>>>(coors, npts, grp, cnt);

    // 3) conv1 via MFMA: dense bf16 (in d_out) -> mid bf16 (in d_ws)
    conv1_mfma<<<dim3(6, HO, 4), 256, 0, stream>>>(denseB, W1p, midB);

    // 4) re-zero all of d_out, then MFMA masked deconv -> NCHW out
    zero_f4<<<2048, 256, 0, stream>>>((float4*)d_out, n4);
    int pblocks = (npts + 63) / 64;
    conv2_mfma<<<dim3(pblocks, 4), 256, 0, stream>>>(midB, W2p, coors, grp, cnt, out, npts);
}

// Round 7
// 209.677 us; speedup vs baseline: 6.0090x; 1.2700x over previous
//
#include <hip/hip_runtime.h>

#define HH 383
#define WW 383
#define CINC 64
#define COUTC 128
#define HO 191
#define WO 191
#define MIDN (4L * HO * WO * COUTC)   // 18,690,048 elements
#define NIDX (4 * HH * WW)            // 586,756 pixels

typedef __attribute__((ext_vector_type(8))) short short8;
typedef __attribute__((ext_vector_type(8))) unsigned short ushort8;
typedef __attribute__((ext_vector_type(4))) float f32x4;

static __device__ inline unsigned short f2bf(float f) {
    unsigned u = __float_as_uint(f);
    unsigned r = (u + 0x7FFFu + ((u >> 16) & 1u)) >> 16;
    return (unsigned short)r;
}

// ---------------- zero (float4 granularity) ----------------
__global__ void zero_f4(float4* __restrict__ p, long n4) {
    long i = blockIdx.x * (long)blockDim.x + threadIdx.x;
    long stride = (long)gridDim.x * blockDim.x;
    float4 z = make_float4(0.f, 0.f, 0.f, 0.f);
    for (; i < n4; i += stride) p[i] = z;
}

// ---------------- scatter features -> dense NHWC bf16 (in d_out) ----------------
__global__ void scatter_feats_bf16(const float* __restrict__ feats,
                                   const int* __restrict__ coors,
                                   unsigned short* __restrict__ dense, int npts) {
    int t = blockIdx.x * blockDim.x + threadIdx.x;
    if (t >= npts * 8) return;
    int p = t >> 3, q = t & 7;
    int b = coors[3 * p], y = coors[3 * p + 1], x = coors[3 * p + 2];
    const float* f = feats + (long)p * 64 + q * 8;
    ushort8 v;
    #pragma unroll
    for (int k = 0; k < 8; ++k) v[k] = f2bf(f[k]);
    *(ushort8*)&dense[(((long)b * HH + y) * WW + x) * 64 + q * 8] = v;
}

// ---------------- pack W1 (f32 HWIO) into bf16 MFMA-B fragment layout ----------------
__global__ void w1_prep(const float* __restrict__ W1, unsigned short* __restrict__ W1p) {
    int t = blockIdx.x * blockDim.x + threadIdx.x;
    if (t >= 73728) return;
    int j  = t & 7;
    int l  = (t >> 3) & 63;
    int ng = (t >> 9) & 7;
    int tk = t >> 12;           // tap*2 + kc
    int tap = tk >> 1, kc = tk & 1;
    int ci = kc * 32 + (l >> 4) * 8 + j;
    int co = ng * 16 + (l & 15);
    W1p[t] = f2bf(W1[(tap * 64 + ci) * 128 + co]);
}

// ---------------- pack W2 into bf16 MFMA-B fragments ----------------
__global__ void w2_prep(const float* __restrict__ W2, unsigned short* __restrict__ W2p) {
    int t = blockIdx.x * blockDim.x + threadIdx.x;
    if (t >= 73728) return;
    int j   = t & 7;
    int l   = (t >> 3) & 63;
    int ng  = (t >> 9) & 3;
    int kc  = (t >> 11) & 3;
    int tap = t >> 13;          // 0..8
    int m = kc * 32 + (l >> 4) * 8 + j;
    int c = ng * 16 + (l & 15);
    W2p[t] = f2bf(W2[(tap * 128 + m) * 64 + c]);
}

// ---------------- init: bf16 zero row, group counters, idx = -1 ----------------
__global__ void init_aux(unsigned short* __restrict__ zrow, int* __restrict__ cnt,
                         int* __restrict__ idx) {
    int t = blockIdx.x * blockDim.x + threadIdx.x;
    if (t < 128) zrow[t] = 0;
    if (t < 4) cnt[t] = 0;
    for (int i = t; i < NIDX; i += gridDim.x * blockDim.x) idx[i] = -1;
}

// ---------------- classify points into 4 parity groups (wave-aggregated atomics) ----------------
__global__ void classify(const int* __restrict__ coors, int npts,
                         int* __restrict__ grp, int* __restrict__ cnt) {
    int t = blockIdx.x * blockDim.x + threadIdx.x;
    int lane = threadIdx.x & 63;
    int g = -1;
    if (t < npts) {
        int y = coors[3 * t + 1], x = coors[3 * t + 2];
        g = (y & 1) * 2 + (x & 1);
    }
    #pragma unroll
    for (int gg = 0; gg < 4; ++gg) {
        unsigned long long mask = __ballot(g == gg);
        if (!mask) continue;
        int leader = __ffsll((long long)mask) - 1;
        int base = 0;
        if (lane == leader) base = atomicAdd(&cnt[gg], __popcll(mask));
        base = __shfl(base, leader);
        if (g == gg) {
            int rank = __popcll(mask & ((1ULL << lane) - 1ULL));
            grp[gg * npts + base + rank] = t;
        }
    }
}

// ---------------- build pixel -> compact-id map ----------------
__global__ void idx_build(const int* __restrict__ coors, const int* __restrict__ grp,
                          const int* __restrict__ cnt, int* __restrict__ idx, int npts) {
    int t = blockIdx.x * blockDim.x + threadIdx.x;
    if (t >= 4 * npts) return;
    int g = t / npts, k = t - g * npts;
    if (k >= cnt[g]) return;
    int base = 0;
    if (g > 0) base += cnt[0];
    if (g > 1) base += cnt[1];
    if (g > 2) base += cnt[2];
    int p = grp[g * npts + k];
    int b = coors[3 * p], y = coors[3 * p + 1], x = coors[3 * p + 2];
    idx[(b * HH + y) * WW + x] = base + k;
}

// ---------------- conv1: 3x3 stride-2 VALID via bf16 MFMA implicit GEMM ----------------
__global__ __launch_bounds__(256, 4) void conv1_mfma(const unsigned short* __restrict__ dense,
                                                     const unsigned short* __restrict__ W1p,
                                                     unsigned short* __restrict__ mid) {
    __shared__ unsigned short lds[3 * 66 * 64];
    const int j0 = blockIdx.x * 32;
    const int i  = blockIdx.y;
    const int b  = blockIdx.z;
    const int tid = threadIdx.x;
    const int w = tid >> 6, l = tid & 63;

    for (int t = tid; t < 3 * 66 * 8; t += 256) {
        int r = t / 528;
        int rem = t - r * 528;
        int xx = rem >> 3, c8 = rem & 7;
        int gx = 2 * j0 + xx;
        uint4 v = make_uint4(0u, 0u, 0u, 0u);
        if (gx < WW)
            v = *(const uint4*)&dense[(((long)b * HH + (2 * i + r)) * WW + gx) * 64 + c8 * 8];
        int sidx = (r * 66 + xx) * 64 + ((c8 ^ ((xx >> 1) & 7)) << 3);
        *(uint4*)&lds[sidx] = v;
    }
    __syncthreads();

    const int pj0 = l & 15;
    const int hi8 = (l >> 4) * 8;
    f32x4 zf = {0.f, 0.f, 0.f, 0.f};
    f32x4 acc[2][2] = {{zf, zf}, {zf, zf}};

    for (int ky = 0; ky < 3; ++ky) {
        for (int kx = 0; kx < 3; ++kx) {
            const int tap = ky * 3 + kx;
            #pragma unroll
            for (int kc = 0; kc < 2; ++kc) {
                int fo = (((tap * 2 + kc) * 8 + 2 * w) << 9) + l * 8;
                short8 b0 = *(const short8*)&W1p[fo];
                short8 b1 = *(const short8*)&W1p[fo + 512];
                #pragma unroll
                for (int mt = 0; mt < 2; ++mt) {
                    int pj = pj0 + mt * 16;
                    int xx = 2 * pj + kx;
                    int idx = ((ky * 66 + xx) * 64 + kc * 32 + hi8) ^ (((xx >> 1) & 7) << 3);
                    short8 a = *(const short8*)&lds[idx];
                    acc[mt][0] = __builtin_amdgcn_mfma_f32_16x16x32_bf16(a, b0, acc[mt][0], 0, 0, 0);
                    acc[mt][1] = __builtin_amdgcn_mfma_f32_16x16x32_bf16(a, b1, acc[mt][1], 0, 0, 0);
                }
            }
        }
    }

    const int n0 = 32 * w + (l & 15);
    const int rowbase = (l >> 4) * 4;
    #pragma unroll
    for (int mt = 0; mt < 2; ++mt) {
        #pragma unroll
        for (int reg = 0; reg < 4; ++reg) {
            int j = j0 + mt * 16 + rowbase + reg;
            if (j < WO) {
                long base = (((long)b * HO + i) * WO + j) * COUTC;
                mid[base + n0]      = f2bf(acc[mt][0][reg]);
                mid[base + n0 + 16] = f2bf(acc[mt][1][reg]);
            }
        }
    }
}

// ---------------- conv2: parity-grouped masked deconv via bf16 MFMA gather-GEMM ----------------
// Writes compact res[point][64c] instead of scattered NCHW.
__global__ __launch_bounds__(256, 4) void conv2_mfma(const unsigned short* __restrict__ mid,
                                                     const unsigned short* __restrict__ W2p,
                                                     const int* __restrict__ coors,
                                                     const int* __restrict__ grp,
                                                     const int* __restrict__ cnt,
                                                     float* __restrict__ res, int npts) {
    __shared__ int meta[64 * 3];

    const int g  = blockIdx.y;
    const int n  = cnt[g];
    const int p0 = blockIdx.x * 64;
    if (p0 >= n) return;
    int gbase = 0;
    if (g > 0) gbase += cnt[0];
    if (g > 1) gbase += cnt[1];
    if (g > 2) gbase += cnt[2];

    const int gy = g >> 1, gx = g & 1;
    const int tid = threadIdx.x, l = tid & 63, w = tid >> 6;

    if (tid < 64) {
        int pp = p0 + tid;
        if (pp < n) {
            int t = grp[g * npts + pp];
            meta[tid * 3 + 0] = coors[3 * t + 0];
            meta[tid * 3 + 1] = coors[3 * t + 1];
            meta[tid * 3 + 2] = coors[3 * t + 2];
        } else {
            meta[tid * 3 + 1] = -1;
        }
    }
    __syncthreads();

    const int pA = w * 16 + (l & 15);
    const int bA = meta[pA * 3 + 0];
    const int yA = meta[pA * 3 + 1];
    const int xA = meta[pA * 3 + 2];
    const int hi8 = (l >> 4) * 8;

    f32x4 zf = {0.f, 0.f, 0.f, 0.f};
    f32x4 acc[4] = {zf, zf, zf, zf};

    const int nsy = gy ? 1 : 2, nsx = gx ? 1 : 2;
    for (int sy = 0; sy < nsy; ++sy) {
        const int ky = gy ? 1 : sy * 2;
        const int i  = gy ? (yA >> 1) : ((yA >> 1) - 1 + sy);
        for (int sx = 0; sx < nsx; ++sx) {
            const int kx = gx ? 1 : sx * 2;
            const int j  = gx ? (xA >> 1) : ((xA >> 1) - 1 + sx);
            const int tap = ky * 3 + kx;
            bool ok = (yA >= 0) && (unsigned)i < (unsigned)HO && (unsigned)j < (unsigned)WO;
            int offA = ok ? ((bA * HO + i) * WO + j) * COUTC : (int)MIDN;

            #pragma unroll
            for (int kc = 0; kc < 4; ++kc) {
                short8 a = *(const short8*)&mid[offA + kc * 32 + hi8];
                const unsigned short* wp = &W2p[((tap * 4 + kc) * 4) * 512 + l * 8];
                short8 b0 = *(const short8*)&wp[0];
                short8 b1 = *(const short8*)&wp[512];
                short8 b2 = *(const short8*)&wp[1024];
                short8 b3 = *(const short8*)&wp[1536];
                acc[0] = __builtin_amdgcn_mfma_f32_16x16x32_bf16(a, b0, acc[0], 0, 0, 0);
                acc[1] = __builtin_amdgcn_mfma_f32_16x16x32_bf16(a, b1, acc[1], 0, 0, 0);
                acc[2] = __builtin_amdgcn_mfma_f32_16x16x32_bf16(a, b2, acc[2], 0, 0, 0);
                acc[3] = __builtin_amdgcn_mfma_f32_16x16x32_bf16(a, b3, acc[3], 0, 0, 0);
            }
        }
    }

    // epilogue: compact store. D col = l&15 (cout in group), row = (l>>4)*4+reg (point)
    #pragma unroll
    for (int reg = 0; reg < 4; ++reg) {
        int pl = w * 16 + (l >> 4) * 4 + reg;
        if (p0 + pl < n) {
            float* rp = &res[(long)(gbase + p0 + pl) * 64 + (l & 15)];
            #pragma unroll
            for (int ng = 0; ng < 4; ++ng) rp[ng * 16] = acc[ng][reg];
        }
    }
}

// ---------------- expand: compact res + idx map -> dense NCHW output (coalesced) ----------------
__global__ __launch_bounds__(256) void expand(const float4* __restrict__ res4,
                                              const int* __restrict__ idx,
                                              float* __restrict__ out) {
    const int y = blockIdx.x, b = blockIdx.y;
    const int tid = threadIdx.x;
    const long plane = (long)HH * WW;
    const int rbase = (b * HH + y) * WW;

    #pragma unroll
    for (int half = 0; half < 2; ++half) {
        int x = half * 256 + tid;
        if (x < WW) {
            int id = idx[rbase + x];
            long obase = (long)b * 64 * plane + (long)y * WW + x;
            #pragma unroll 4
            for (int c4 = 0; c4 < 16; ++c4) {
                float4 v = make_float4(0.f, 0.f, 0.f, 0.f);
                if (id >= 0) v = res4[(long)id * 16 + c4];
                out[obase + (c4 * 4 + 0) * plane] = v.x;
                out[obase + (c4 * 4 + 1) * plane] = v.y;
                out[obase + (c4 * 4 + 2) * plane] = v.z;
                out[obase + (c4 * 4 + 3) * plane] = v.w;
            }
        }
    }
}

extern "C" void kernel_launch(void* const* d_in, const int* in_sizes, int n_in,
                              void* d_out, int out_size, void* d_ws, size_t ws_size,
                              hipStream_t stream) {
    const float* feats = (const float*)d_in[0];
    const int* coors = (const int*)d_in[1];
    const float* W1 = (const float*)d_in[3];
    const float* W2 = (const float*)d_in[4];
    float* out = (float*)d_out;
    int npts = in_sizes[1] / 3;

    // d_ws layout (bytes):
    //   midB   [0, 37,380,096)            bf16 mid
    //   zrowB  +256
    //   grp    4*npts ints
    //   cnt    4 ints (+pad to 16B)
    //   W2p    73728 ushorts
    //   idx    NIDX ints
    //   res    npts*64 floats (16B-aligned)
    char* wsb = (char*)d_ws;
    unsigned short* midB  = (unsigned short*)wsb;
    unsigned short* zrowB = (unsigned short*)(wsb + 37380096);
    int*   grp = (int*)(wsb + 37380096 + 256);
    char*  p   = wsb + 37380096 + 256 + (size_t)4 * npts * 4;
    int*   cnt = (int*)p;                 p += 16;
    unsigned short* W2p = (unsigned short*)p;  p += 73728 * 2;
    int*   idx = (int*)p;                 p += (size_t)NIDX * 4;
    size_t off = (size_t)(p - wsb);
    off = (off + 15) & ~(size_t)15;
    float* res = (float*)(wsb + off);

    // d_out scratch: [0, 75.1MB) dense bf16; [120MB, +147KB) packed W1
    unsigned short* denseB = (unsigned short*)d_out;
    unsigned short* W1p = (unsigned short*)((float*)d_out + 30000000L);

    long n4 = (long)out_size / 4;

    // 1) pack weights; zero dense region; scatter features as bf16 dense NHWC
    w1_prep<<<288, 256, 0, stream>>>(W1, W1p);
    w2_prep<<<288, 256, 0, stream>>>(W2, W2p);
    zero_f4<<<2048, 256, 0, stream>>>((float4*)d_out, n4 / 2);
    scatter_feats_bf16<<<(npts * 8 + 255) / 256, 256, 0, stream>>>(feats, coors, denseB, npts);

    // 2) parity classification + pixel->compact-id map
    init_aux<<<512, 256, 0, stream>>>(zrowB, cnt, idx);
    classify<<<(npts + 255) / 256, 256, 0, stream>>>(coors, npts, grp, cnt);
    idx_build<<<(4 * npts + 255) / 256, 256, 0, stream>>>(coors, grp, cnt, idx, npts);

    // 3) conv1 via MFMA: dense bf16 (in d_out) -> mid bf16 (in d_ws)
    conv1_mfma<<<dim3(6, HO, 4), 256, 0, stream>>>(denseB, W1p, midB);

    // 4) conv2 via MFMA -> compact res
    int pblocks = (npts + 63) / 64;
    conv2_mfma<<<dim3(pblocks, 4), 256, 0, stream>>>(midB, W2p, coors, grp, cnt, res, npts);

    // 5) expand compact res to dense NCHW output (writes every element)
    expand<<<dim3(HH, 4), 256, 0, stream>>>((const float4*)res, idx, out);
}

// Round 8
// 180.874 us; speedup vs baseline: 6.9658x; 1.1592x over previous
//
#include <hip/hip_runtime.h>

#define HH 383
#define WW 383
#define CINC 64
#define COUTC 128
#define HO 191
#define WO 191
#define MIDN (4L * HO * WO * COUTC)   // 18,690,048 elements
#define NIDX (4 * HH * WW)            // 586,756 pixels

typedef __attribute__((ext_vector_type(8))) short short8;
typedef __attribute__((ext_vector_type(8))) unsigned short ushort8;
typedef __attribute__((ext_vector_type(4))) float f32x4;

static __device__ inline unsigned short f2bf(float f) {
    unsigned u = __float_as_uint(f);
    unsigned r = (u + 0x7FFFu + ((u >> 16) & 1u)) >> 16;
    return (unsigned short)r;
}

// ---------------- prep: pack W1/W2 to bf16 MFMA-B fragments, zero row, counters, idx=-1 ----------------
__global__ void prep(const float* __restrict__ W1, const float* __restrict__ W2,
                     unsigned short* __restrict__ W1p, unsigned short* __restrict__ W2p,
                     unsigned short* __restrict__ zrow, int* __restrict__ cnt,
                     int* __restrict__ idx) {
    int t = blockIdx.x * blockDim.x + threadIdx.x;
    int N = gridDim.x * blockDim.x;
    if (t < 73728) {
        // W1p[((tap*2+kc)*8+ng)*512 + l*8 + j] = W1[(tap*64 + kc*32+(l>>4)*8+j)*128 + ng*16+(l&15)]
        int j  = t & 7;
        int l  = (t >> 3) & 63;
        int ng = (t >> 9) & 7;
        int tk = t >> 12;
        int tap = tk >> 1, kc = tk & 1;
        int ci = kc * 32 + (l >> 4) * 8 + j;
        int co = ng * 16 + (l & 15);
        W1p[t] = f2bf(W1[(tap * 64 + ci) * 128 + co]);
        // W2p[((tap*4+kc)*4+ng)*512 + l*8 + j] = W2[(tap*128 + kc*32+(l>>4)*8+j)*64 + ng*16+(l&15)]
        int ng2  = (t >> 9) & 3;
        int kc2  = (t >> 11) & 3;
        int tap2 = t >> 13;
        int m = kc2 * 32 + (l >> 4) * 8 + j;
        int c = ng2 * 16 + (l & 15);
        W2p[t] = f2bf(W2[(tap2 * 128 + m) * 64 + c]);
    }
    if (t < 128) zrow[t] = 0;
    if (t < 4) cnt[t] = 0;
    for (int i = t; i < NIDX; i += N) idx[i] = -1;
}

// ---------------- classify: parity groups (wave-aggregated atomics) + pixel->point map ----------------
__global__ void classify(const int* __restrict__ coors, int npts,
                         int* __restrict__ grp, int* __restrict__ cnt,
                         int* __restrict__ idx) {
    int t = blockIdx.x * blockDim.x + threadIdx.x;
    int lane = threadIdx.x & 63;
    int g = -1;
    if (t < npts) {
        int b = coors[3 * t], y = coors[3 * t + 1], x = coors[3 * t + 2];
        g = (y & 1) * 2 + (x & 1);
        idx[(b * HH + y) * WW + x] = t;
    }
    #pragma unroll
    for (int gg = 0; gg < 4; ++gg) {
        unsigned long long mask = __ballot(g == gg);
        if (!mask) continue;
        int leader = __ffsll((long long)mask) - 1;
        int base = 0;
        if (lane == leader) base = atomicAdd(&cnt[gg], __popcll(mask));
        base = __shfl(base, leader);
        if (g == gg) {
            int rank = __popcll(mask & ((1ULL << lane) - 1ULL));
            grp[gg * npts + base + rank] = t;
        }
    }
}

// ---------------- conv1: 3x3 stride-2 VALID via bf16 MFMA, gather-staged from sparse feats ----------------
__global__ __launch_bounds__(256, 4) void conv1_mfma(const float* __restrict__ feats,
                                                     const int* __restrict__ idxm,
                                                     const unsigned short* __restrict__ W1p,
                                                     unsigned short* __restrict__ mid) {
    __shared__ unsigned short lds[3 * 66 * 64];
    const int j0 = blockIdx.x * 32;
    const int i  = blockIdx.y;
    const int b  = blockIdx.z;
    const int tid = threadIdx.x;
    const int w = tid >> 6, l = tid & 63;

    // stage rows 2i..2i+2, x = 2*j0 .. 2*j0+65: gather active points via idx map, bf16-convert
    for (int t = tid; t < 3 * 66 * 8; t += 256) {
        int r = t / 528;
        int rem = t - r * 528;
        int xx = rem >> 3, c8 = rem & 7;
        int gx = 2 * j0 + xx;
        ushort8 v = {0, 0, 0, 0, 0, 0, 0, 0};
        if (gx < WW) {
            int id = idxm[((b * HH + 2 * i + r) * WW + gx)];
            if (id >= 0) {
                const float* f = feats + (long)id * 64 + c8 * 8;
                #pragma unroll
                for (int k = 0; k < 8; ++k) v[k] = f2bf(f[k]);
            }
        }
        int sidx = (r * 66 + xx) * 64 + ((c8 ^ ((xx >> 1) & 7)) << 3);
        *(ushort8*)&lds[sidx] = v;
    }
    __syncthreads();

    const int pj0 = l & 15;
    const int hi8 = (l >> 4) * 8;
    f32x4 zf = {0.f, 0.f, 0.f, 0.f};
    f32x4 acc[2][2] = {{zf, zf}, {zf, zf}};

    for (int ky = 0; ky < 3; ++ky) {
        for (int kx = 0; kx < 3; ++kx) {
            const int tap = ky * 3 + kx;
            #pragma unroll
            for (int kc = 0; kc < 2; ++kc) {
                int fo = (((tap * 2 + kc) * 8 + 2 * w) << 9) + l * 8;
                short8 b0 = *(const short8*)&W1p[fo];
                short8 b1 = *(const short8*)&W1p[fo + 512];
                #pragma unroll
                for (int mt = 0; mt < 2; ++mt) {
                    int pj = pj0 + mt * 16;
                    int xx = 2 * pj + kx;
                    int idx2 = ((ky * 66 + xx) * 64 + kc * 32 + hi8) ^ (((xx >> 1) & 7) << 3);
                    short8 a = *(const short8*)&lds[idx2];
                    acc[mt][0] = __builtin_amdgcn_mfma_f32_16x16x32_bf16(a, b0, acc[mt][0], 0, 0, 0);
                    acc[mt][1] = __builtin_amdgcn_mfma_f32_16x16x32_bf16(a, b1, acc[mt][1], 0, 0, 0);
                }
            }
        }
    }

    const int n0 = 32 * w + (l & 15);
    const int rowbase = (l >> 4) * 4;
    #pragma unroll
    for (int mt = 0; mt < 2; ++mt) {
        #pragma unroll
        for (int reg = 0; reg < 4; ++reg) {
            int j = j0 + mt * 16 + rowbase + reg;
            if (j < WO) {
                long base = (((long)b * HO + i) * WO + j) * COUTC;
                mid[base + n0]      = f2bf(acc[mt][0][reg]);
                mid[base + n0 + 16] = f2bf(acc[mt][1][reg]);
            }
        }
    }
}

// ---------------- conv2: parity-grouped masked deconv via bf16 MFMA gather-GEMM ----------------
// Writes compact res[point_id][64c] (point_id = original point index).
__global__ __launch_bounds__(256, 4) void conv2_mfma(const unsigned short* __restrict__ mid,
                                                     const unsigned short* __restrict__ W2p,
                                                     const int* __restrict__ coors,
                                                     const int* __restrict__ grp,
                                                     const int* __restrict__ cnt,
                                                     float* __restrict__ res, int npts) {
    __shared__ int meta[64 * 4];

    const int g  = blockIdx.y;
    const int n  = cnt[g];
    const int p0 = blockIdx.x * 64;
    if (p0 >= n) return;
    const int gy = g >> 1, gx = g & 1;
    const int tid = threadIdx.x, l = tid & 63, w = tid >> 6;

    if (tid < 64) {
        int pp = p0 + tid;
        if (pp < n) {
            int t = grp[g * npts + pp];
            meta[tid * 4 + 0] = coors[3 * t + 0];
            meta[tid * 4 + 1] = coors[3 * t + 1];
            meta[tid * 4 + 2] = coors[3 * t + 2];
            meta[tid * 4 + 3] = t;
        } else {
            meta[tid * 4 + 1] = -1;
        }
    }
    __syncthreads();

    const int pA = w * 16 + (l & 15);
    const int bA = meta[pA * 4 + 0];
    const int yA = meta[pA * 4 + 1];
    const int xA = meta[pA * 4 + 2];
    const int hi8 = (l >> 4) * 8;

    f32x4 zf = {0.f, 0.f, 0.f, 0.f};
    f32x4 acc[4] = {zf, zf, zf, zf};

    const int nsy = gy ? 1 : 2, nsx = gx ? 1 : 2;
    for (int sy = 0; sy < nsy; ++sy) {
        const int ky = gy ? 1 : sy * 2;
        const int i  = gy ? (yA >> 1) : ((yA >> 1) - 1 + sy);
        for (int sx = 0; sx < nsx; ++sx) {
            const int kx = gx ? 1 : sx * 2;
            const int j  = gx ? (xA >> 1) : ((xA >> 1) - 1 + sx);
            const int tap = ky * 3 + kx;
            bool ok = (yA >= 0) && (unsigned)i < (unsigned)HO && (unsigned)j < (unsigned)WO;
            int offA = ok ? ((bA * HO + i) * WO + j) * COUTC : (int)MIDN;

            #pragma unroll
            for (int kc = 0; kc < 4; ++kc) {
                short8 a = *(const short8*)&mid[offA + kc * 32 + hi8];
                const unsigned short* wp = &W2p[((tap * 4 + kc) * 4) * 512 + l * 8];
                short8 b0 = *(const short8*)&wp[0];
                short8 b1 = *(const short8*)&wp[512];
                short8 b2 = *(const short8*)&wp[1024];
                short8 b3 = *(const short8*)&wp[1536];
                acc[0] = __builtin_amdgcn_mfma_f32_16x16x32_bf16(a, b0, acc[0], 0, 0, 0);
                acc[1] = __builtin_amdgcn_mfma_f32_16x16x32_bf16(a, b1, acc[1], 0, 0, 0);
                acc[2] = __builtin_amdgcn_mfma_f32_16x16x32_bf16(a, b2, acc[2], 0, 0, 0);
                acc[3] = __builtin_amdgcn_mfma_f32_16x16x32_bf16(a, b3, acc[3], 0, 0, 0);
            }
        }
    }

    // epilogue: D col = l&15 (cout in group), row = (l>>4)*4+reg (point in m-tile)
    #pragma unroll
    for (int reg = 0; reg < 4; ++reg) {
        int pl = w * 16 + (l >> 4) * 4 + reg;
        if (meta[pl * 4 + 1] >= 0) {
            int pt = meta[pl * 4 + 3];
            float* rp = &res[(long)pt * 64 + (l & 15)];
            #pragma unroll
            for (int ng = 0; ng < 4; ++ng) rp[ng * 16] = acc[ng][reg];
        }
    }
}

// ---------------- expand: compact res + idx map -> dense NCHW output (coalesced) ----------------
__global__ __launch_bounds__(256) void expand(const float4* __restrict__ res4,
                                              const int* __restrict__ idx,
                                              float* __restrict__ out) {
    const int y = blockIdx.x, b = blockIdx.y;
    const int tid = threadIdx.x;
    const long plane = (long)HH * WW;
    const int rbase = (b * HH + y) * WW;

    #pragma unroll
    for (int half = 0; half < 2; ++half) {
        int x = half * 256 + tid;
        if (x < WW) {
            int id = idx[rbase + x];
            long obase = (long)b * 64 * plane + (long)y * WW + x;
            #pragma unroll 4
            for (int c4 = 0; c4 < 16; ++c4) {
                float4 v = make_float4(0.f, 0.f, 0.f, 0.f);
                if (id >= 0) v = res4[(long)id * 16 + c4];
                out[obase + (c4 * 4 + 0) * plane] = v.x;
                out[obase + (c4 * 4 + 1) * plane] = v.y;
                out[obase + (c4 * 4 + 2) * plane] = v.z;
                out[obase + (c4 * 4 + 3) * plane] = v.w;
            }
        }
    }
}

extern "C" void kernel_launch(void* const* d_in, const int* in_sizes, int n_in,
                              void* d_out, int out_size, void* d_ws, size_t ws_size,
                              hipStream_t stream) {
    const float* feats = (const float*)d_in[0];
    const int* coors = (const int*)d_in[1];
    const float* W1 = (const float*)d_in[3];
    const float* W2 = (const float*)d_in[4];
    float* out = (float*)d_out;
    int npts = in_sizes[1] / 3;

    // d_ws layout (bytes):
    //   midB  [0, 37,380,096)  bf16 mid
    //   zrowB +256
    //   W1p   73728 ushorts
    //   W2p   73728 ushorts
    //   cnt   4 ints (+pad 16)
    //   grp   4*npts ints
    //   idx   NIDX ints
    //   res   npts*64 floats (16B aligned)
    char* wsb = (char*)d_ws;
    unsigned short* midB  = (unsigned short*)wsb;
    unsigned short* zrowB = (unsigned short*)(wsb + 37380096);
    unsigned short* W1p = (unsigned short*)(wsb + 37380096 + 256);
    unsigned short* W2p = W1p + 73728;
    int* cnt = (int*)(W2p + 73728);
    int* grp = cnt + 4;
    int* idx = grp + 4 * npts;
    char* pend = (char*)(idx + NIDX);
    size_t off = ((size_t)(pend - wsb) + 15) & ~(size_t)15;
    float* res = (float*)(wsb + off);

    // 1) fused prep: pack W1/W2, zero row, counters, idx=-1
    prep<<<288, 256, 0, stream>>>(W1, W2, W1p, W2p, zrowB, cnt, idx);

    // 2) classify: parity groups + pixel->point map
    classify<<<(npts + 255) / 256, 256, 0, stream>>>(coors, npts, grp, cnt, idx);

    // 3) conv1 via MFMA (gather-staged from sparse feats) -> mid bf16
    conv1_mfma<<<dim3(6, HO, 4), 256, 0, stream>>>(feats, idx, W1p, midB);

    // 4) conv2 via MFMA -> compact res (indexed by original point id)
    int pblocks = (npts + 63) / 64;
    conv2_mfma<<<dim3(pblocks, 4), 256, 0, stream>>>(midB, W2p, coors, grp, cnt, res, npts);

    // 5) expand compact res to dense NCHW output (writes every element)
    expand<<<dim3(HH, 4), 256, 0, stream>>>((const float4*)res, idx, out);
}